// Round 21
// baseline (74.126 us; speedup 1.0000x reference)
//
#include <hip/hip_runtime.h>
#include <hip/hip_bf16.h>
#include <stdint.h>

#define BROWS 16384
#define DIM   256
#define BM    128               // A rows per block
#define NBM   (BROWS / BM)      // 128 row blocks
#define NBNR  16                // col-range blocks; each covers 1024 cols
#define NSTG  8                 // 128-col stages per block (16 KB each)
#define NCHUNK 32               // per-row partial chunks (16 bnr x 2 wch)

#define LOG2E 1.44269504088896340736f

typedef __attribute__((ext_vector_type(8))) int  i32x8;
typedef __attribute__((ext_vector_type(4))) float f32x4;
typedef __attribute__((ext_vector_type(2))) float f32x2;
typedef unsigned char uchar;

__device__ __forceinline__ void gload_lds16(const void* g, void* l) {
  __builtin_amdgcn_global_load_lds(
      (const __attribute__((address_space(1))) void*)g,
      (__attribute__((address_space(3))) void*)l, 16, 0, 0);
}

// e2m1 RTN: grid {0,.5,1,1.5,2,3,4,6}, monotonic enc 0..7, sign = bit3.
__device__ __forceinline__ unsigned q4(float x) {
  float a = fabsf(x);
  unsigned q = (a >= 0.25f) + (a >= 0.75f) + (a >= 1.25f) + (a >= 1.75f) +
               (a >= 2.5f) + (a >= 3.5f) + (a >= 5.0f);
  return q | ((__float_as_uint(x) >> 28) & 8u);
}

// Tiled fp4 layout ("frag-major", r16-r19-verified): row r, 32-elem K-chunk c:
//   byte addr = (r>>4)*2048 + c*256 + (r&15)*16 + b(0..15)
// Wave frag (lane l: row 16g+(l&15), K-chunk kt*4+(l>>4)) = g*2048 + kt*1024
// + l*16 -> 1KB contiguous per frag.

// ---------------- Kernel A: normalize BOTH matrices -> tiled fp4 + diag -----
__global__ void normalize_both(const float* __restrict__ o,
                               const float* __restrict__ t,
                               uchar* __restrict__ o4,
                               uchar* __restrict__ t4,
                               float* __restrict__ dlog) {
  int row  = blockIdx.x * 4 + (threadIdx.x >> 6);
  int lane = threadIdx.x & 63;
  float4 a = *(reinterpret_cast<const float4*>(o + (size_t)row * DIM) + lane);
  float4 b = *(reinterpret_cast<const float4*>(t + (size_t)row * DIM) + lane);
  float sso = a.x * a.x + a.y * a.y + a.z * a.z + a.w * a.w;
  float sst = b.x * b.x + b.y * b.y + b.z * b.z + b.w * b.w;
  float d   = a.x * b.x + a.y * b.y + a.z * b.z + a.w * b.w;
#pragma unroll
  for (int m = 1; m < 64; m <<= 1) {
    sso += __shfl_xor(sso, m);
    sst += __shfl_xor(sst, m);
    d   += __shfl_xor(d, m);
  }
  float ro = rsqrtf(sso);
  float rt = rsqrtf(sst);
  if (lane == 0) dlog[row] = d * ro * rt;
  float qo = ro * (16.0f * LOG2E);   // A carries log2e
  float qt = rt * 16.0f;
  unsigned wo = q4(a.x * qo) | (q4(a.y * qo) << 4) |
                (q4(a.z * qo) << 8) | (q4(a.w * qo) << 12);
  unsigned wt = q4(b.x * qt) | (q4(b.y * qt) << 4) |
                (q4(b.z * qt) << 8) | (q4(b.w * qt) << 12);
  size_t taddr = (size_t)(row >> 4) * 2048 + (size_t)((lane >> 3) * 256) +
                 (size_t)((row & 15) * 16) + (size_t)((lane & 7) * 2);
  *reinterpret_cast<unsigned short*>(o4 + taddr) = (unsigned short)wo;
  *reinterpret_cast<unsigned short*>(t4 + taddr) = (unsigned short)wt;
}

// ---------------- Kernel B: persistent-A fp4 GEMM, B via 16KB-stage LDS -----
// r19 structure (proven best: 47.6us, 62% occ, 0 conflicts). One change:
// exp2 replaced by a PACKED degree-5 polynomial (v_pk_fma_f32, 2 elems/inst,
// full-rate pipe) -- v_exp_f32 is quarter-rate and was ~14us of the ~27us
// VALU-pipe time. 2^x = e^(x ln2), Horner c_k=(ln2)^k/k!; |x|<=1.45 ->
// rel err <= 2e-3 worst-case (typ. 2e-6), loss err << 0.19 threshold.
// mfma_scale_16x16x128 FP4 (cbsz=4, blgp=4), E8M0 scales 0x7B = 2^-4.
// Frag: lane l holds row (l&15), K-chunk (l>>4), data in dwords 0..3.
// C/D: col = lane&15, row = (lane>>4)*4 + reg.
__global__ __launch_bounds__(512, 8) void gemm_expsum(
    const uchar* __restrict__ A4,   // ohat fp4 tiled (x16*log2e)
    const uchar* __restrict__ B4,   // that fp4 tiled (x16)
    float* __restrict__ partial) {
  __shared__ __align__(16) uchar Bs[2][16384];  // 2 x 16 KB

  int b   = blockIdx.x;
  int xcd = b & 7;
  int idx = b >> 3;               // 0..255
  int bm  = xcd * 16 + (idx & 15);
  int bnr = idx >> 4;             // 0..15

  int tid  = threadIdx.x;
  int lane = tid & 63;
  int wid  = tid >> 6;            // 0..7
  int wr   = wid & 3;             // 32-row strip
  int wch  = wid >> 2;            // 64-col half of each 128-col stage

  const uchar* Ap = A4 + (size_t)(bm * 8 + wr * 2) * 2048 + (size_t)lane * 16;
  const uchar* Bg = B4 + (size_t)bnr * 131072;   // 128 KB strip (1024 cols)

  // persistent A fragments: data 4 dwords, upper 4 dead for FP4
  i32x8 af[2][2];
#pragma unroll
  for (int m = 0; m < 2; ++m)
#pragma unroll
    for (int kt = 0; kt < 2; ++kt) {
      int4 d = *reinterpret_cast<const int4*>(Ap + m * 2048 + kt * 1024);
      af[m][kt] = (i32x8){d.x, d.y, d.z, d.w, 0, 0, 0, 0};
    }

  f32x2 v2[4];
#pragma unroll
  for (int j = 0; j < 4; ++j) v2[j] = (f32x2){0.f, 0.f};

  const f32x4 zero4 = {0.f, 0.f, 0.f, 0.f};
  i32x8 b0 = (i32x8){0, 0, 0, 0, 0, 0, 0, 0};
  i32x8 b1 = (i32x8){0, 0, 0, 0, 0, 0, 0, 0};

  // packed 2^x: deg-5 Horner, c_k = (ln2)^k/k!; 5 pk_fma + 1 pk_add per pair
  const f32x2 C5 = {0.0013333558f, 0.0013333558f};
  const f32x2 C4 = {0.0096181291f, 0.0096181291f};
  const f32x2 C3 = {0.0555041087f, 0.0555041087f};
  const f32x2 C2 = {0.2402265070f, 0.2402265070f};
  const f32x2 C1 = {0.6931471806f, 0.6931471806f};
  const f32x2 C0 = {1.0f, 1.0f};

#define PACC(dst, lo, hi)                                                      \
  {                                                                            \
    f32x2 x2 = {lo, hi};                                                       \
    f32x2 p  = __builtin_elementwise_fma(C5, x2, C4);                          \
    p = __builtin_elementwise_fma(p, x2, C3);                                  \
    p = __builtin_elementwise_fma(p, x2, C2);                                  \
    p = __builtin_elementwise_fma(p, x2, C1);                                  \
    p = __builtin_elementwise_fma(p, x2, C0);                                  \
    dst += p;                                                                  \
  }

  // stage st (16 KB = 128 cols): 2 x 16B gload per thread, linear both sides.
#define STAGE(st, s)                                                           \
  {                                                                            \
    _Pragma("unroll") for (int p = 0; p < 2; ++p)                              \
        gload_lds16(Bg + (size_t)(st) * 16384 + p * 8192 + wid * 1024 +        \
                        lane * 16,                                             \
                    (char*)Bs[s] + p * 8192 + wid * 1024 + lane * 16);         \
  }

#define COMPUTE(s)                                                             \
  {                                                                            \
    const uchar* bb = Bs[s];                                                   \
    _Pragma("unroll") for (int nn = 0; nn < 4; ++nn) {                         \
      const uchar* cb = bb + (wch * 4 + nn) * 2048 + lane * 16;                \
      *reinterpret_cast<int4*>(&b0) = *reinterpret_cast<const int4*>(cb);      \
      *reinterpret_cast<int4*>(&b1) = *reinterpret_cast<const int4*>(cb + 1024); \
      f32x4 a0 = __builtin_amdgcn_mfma_scale_f32_16x16x128_f8f6f4(             \
          af[0][0], b0, zero4, 4, 4, 0, 0x7B7B7B7B, 0, 0x7B7B7B7B);            \
      f32x4 a1 = __builtin_amdgcn_mfma_scale_f32_16x16x128_f8f6f4(             \
          af[1][0], b0, zero4, 4, 4, 0, 0x7B7B7B7B, 0, 0x7B7B7B7B);            \
      a0 = __builtin_amdgcn_mfma_scale_f32_16x16x128_f8f6f4(                   \
          af[0][1], b1, a0, 4, 4, 0, 0x7B7B7B7B, 0, 0x7B7B7B7B);               \
      a1 = __builtin_amdgcn_mfma_scale_f32_16x16x128_f8f6f4(                   \
          af[1][1], b1, a1, 4, 4, 0, 0x7B7B7B7B, 0, 0x7B7B7B7B);               \
      PACC(v2[0], a0[0], a0[1]);                                               \
      PACC(v2[1], a0[2], a0[3]);                                               \
      PACC(v2[2], a1[0], a1[1]);                                               \
      PACC(v2[3], a1[2], a1[3]);                                               \
    }                                                                          \
  }

  STAGE(0, 0);
  __syncthreads();                 // stage 0 resident
#pragma unroll
  for (int st = 0; st < NSTG; ++st) {
    if (st < NSTG - 1) STAGE(st + 1, (st + 1) & 1);  // async into other buffer
    COMPUTE(st & 1);
    if (st < NSTG - 1) __syncthreads();  // drain stage(st+1); readers of st done
  }
#undef STAGE
#undef COMPUTE
#undef PACC

  // ---- bisect butterfly: v[8] over the 16 fragment columns (r12-verified) ----
  float v[8];
#pragma unroll
  for (int j = 0; j < 8; ++j) v[j] = v2[j >> 1][j & 1];
#pragma unroll
  for (int s = 0; s < 3; ++s) {
    const int len = 8 >> s;
    const int bit = (lane >> s) & 1;
#pragma unroll
    for (int t = 0; t < 4; ++t) {
      if (t < (len >> 1)) {
        float a = v[2 * t], b2 = v[2 * t + 1];
        float recv = __shfl_xor(bit ? a : b2, 1 << s);
        v[t] = (bit ? b2 : a) + recv;
      }
    }
  }
  v[0] += __shfl_xor(v[0], 8);   // complete the 16-lane column sum
  if ((lane & 8) == 0) {
    int j   = lane & 7;          // m = j>>2, r = j&3
    int sub = lane >> 4;         // 0..3
    int row = bm * BM + wr * 32 + (j >> 2) * 16 + sub * 4 + (j & 3);
    partial[(size_t)row * NCHUNK + ((bnr << 1) | wch)] = v[0];
  }
}

// ---------------- Kernel C: per-row finish: log(sum) - exact diag ----------
__global__ void row_finish(const float* __restrict__ partial,
                           const float* __restrict__ dlog,
                           float* __restrict__ rowloss) {
  int row = blockIdx.x * 256 + threadIdx.x;
  const float4* p = reinterpret_cast<const float4*>(partial + (size_t)row * NCHUNK);
  float s = 0.f;
#pragma unroll
  for (int q = 0; q < 8; ++q) {
    float4 pq = p[q];
    s += (pq.x + pq.y) + (pq.z + pq.w);
  }
  rowloss[row] = logf(s) - dlog[row];
}

// ---------------- Kernel D: mean over rows -> d_out[0] ----------------
__global__ void final_reduce(const float* __restrict__ rl, float* __restrict__ out) {
  __shared__ float sm[16];
  float s = 0.f;
  for (int i = threadIdx.x; i < BROWS; i += 1024) s += rl[i];
#pragma unroll
  for (int m = 1; m < 64; m <<= 1) s += __shfl_xor(s, m);
  int wid = threadIdx.x >> 6, lane = threadIdx.x & 63;
  if (lane == 0) sm[wid] = s;
  __syncthreads();
  if (wid == 0) {
    float v = (lane < 16) ? sm[lane] : 0.f;
#pragma unroll
    for (int m = 1; m < 16; m <<= 1) v += __shfl_xor(v, m);
    if (lane == 0) out[0] = v / (float)BROWS;
  }
}

extern "C" void kernel_launch(void* const* d_in, const int* in_sizes, int n_in,
                              void* d_out, int out_size, void* d_ws, size_t ws_size,
                              hipStream_t stream) {
  const float* outputs = (const float*)d_in[0];
  const float* targets = (const float*)d_in[1];
  float* out = (float*)d_out;
  char* ws = (char*)d_ws;

  uchar* o4      = (uchar*)ws;                                      // 2 MB (tiled fp4)
  uchar* t4      = (uchar*)(ws + (size_t)2 * 1024 * 1024);          // 2 MB (tiled fp4)
  float* partial = (float*)(ws + (size_t)4 * 1024 * 1024);          // 2 MB
  float* dlog    = (float*)(ws + (size_t)6 * 1024 * 1024);          // 64 KB
  float* rowloss = (float*)(ws + (size_t)6 * 1024 * 1024 + 65536);  // 64 KB

  normalize_both<<<BROWS / 4, 256, 0, stream>>>(outputs, targets, o4, t4, dlog);
  gemm_expsum<<<NBM * NBNR, 512, 0, stream>>>(o4, t4, partial);
  row_finish<<<BROWS / 256, 256, 0, stream>>>(partial, dlog, rowloss);
  final_reduce<<<1, 1024, 0, stream>>>(rowloss, out);
}

// Round 22
// 63.026 us; speedup vs baseline: 1.1761x; 1.1761x over previous
//
#include <hip/hip_runtime.h>
#include <hip/hip_bf16.h>
#include <stdint.h>

#define BROWS 16384
#define DIM   256
#define BM    128               // A rows per block
#define NBM   (BROWS / BM)      // 128 row blocks
#define NBNR  16                // col-range blocks; each covers 1024 cols
#define NSTG  8                 // 128-col stages per block (16 KB each)
#define NCHUNK 32               // per-row partial chunks (16 bnr x 2 wch)

#define LOG2E 1.44269504088896340736f

typedef __attribute__((ext_vector_type(8))) int  i32x8;
typedef __attribute__((ext_vector_type(4))) float f32x4;
typedef __attribute__((ext_vector_type(2))) float f32x2;
typedef unsigned char uchar;

#if __has_builtin(__builtin_amdgcn_exp2f)
#define EXP2(x) __builtin_amdgcn_exp2f(x)   // bare v_exp_f32 (trans pipe, overlaps VALU)
#else
#define EXP2(x) exp2f(x)
#endif

__device__ __forceinline__ void gload_lds16(const void* g, void* l) {
  __builtin_amdgcn_global_load_lds(
      (const __attribute__((address_space(1))) void*)g,
      (__attribute__((address_space(3))) void*)l, 16, 0, 0);
}

// e2m1 RTN: grid {0,.5,1,1.5,2,3,4,6}, monotonic enc 0..7, sign = bit3.
__device__ __forceinline__ unsigned q4(float x) {
  float a = fabsf(x);
  unsigned q = (a >= 0.25f) + (a >= 0.75f) + (a >= 1.25f) + (a >= 1.75f) +
               (a >= 2.5f) + (a >= 3.5f) + (a >= 5.0f);
  return q | ((__float_as_uint(x) >> 28) & 8u);
}

// Tiled fp4 layout ("frag-major", r16-r21-verified): row r, 32-elem K-chunk c:
//   byte addr = (r>>4)*2048 + c*256 + (r&15)*16 + b(0..15)
// Wave frag (lane l: row 16g+(l&15), K-chunk kt*4+(l>>4)) = g*2048 + kt*1024
// + l*16 -> 1KB contiguous per frag.

// ---------------- Kernel A: normalize BOTH matrices -> tiled fp4 + diag -----
__global__ void normalize_both(const float* __restrict__ o,
                               const float* __restrict__ t,
                               uchar* __restrict__ o4,
                               uchar* __restrict__ t4,
                               float* __restrict__ dlog) {
  int row  = blockIdx.x * 4 + (threadIdx.x >> 6);
  int lane = threadIdx.x & 63;
  float4 a = *(reinterpret_cast<const float4*>(o + (size_t)row * DIM) + lane);
  float4 b = *(reinterpret_cast<const float4*>(t + (size_t)row * DIM) + lane);
  float sso = a.x * a.x + a.y * a.y + a.z * a.z + a.w * a.w;
  float sst = b.x * b.x + b.y * b.y + b.z * b.z + b.w * b.w;
  float d   = a.x * b.x + a.y * b.y + a.z * b.z + a.w * b.w;
#pragma unroll
  for (int m = 1; m < 64; m <<= 1) {
    sso += __shfl_xor(sso, m);
    sst += __shfl_xor(sst, m);
    d   += __shfl_xor(d, m);
  }
  float ro = rsqrtf(sso);
  float rt = rsqrtf(sst);
  if (lane == 0) dlog[row] = d * ro * rt;
  float qo = ro * (16.0f * LOG2E);   // A carries log2e
  float qt = rt * 16.0f;
  unsigned wo = q4(a.x * qo) | (q4(a.y * qo) << 4) |
                (q4(a.z * qo) << 8) | (q4(a.w * qo) << 12);
  unsigned wt = q4(b.x * qt) | (q4(b.y * qt) << 4) |
                (q4(b.z * qt) << 8) | (q4(b.w * qt) << 12);
  size_t taddr = (size_t)(row >> 4) * 2048 + (size_t)((lane >> 3) * 256) +
                 (size_t)((row & 15) * 16) + (size_t)((lane & 7) * 2);
  *reinterpret_cast<unsigned short*>(o4 + taddr) = (unsigned short)wo;
  *reinterpret_cast<unsigned short*>(t4 + taddr) = (unsigned short)wt;
}

// ---------------- Kernel B: persistent-A fp4 GEMM, 64-row wave-strips -------
// Block = 128 A-rows x 1024 cols; 4 waves (256 thr): wr = wid&1 (64-row strip
// = 4 row-groups, af[4][2] persistent), wch = wid>>1 (64-col half of each
// 128-col stage). vs r19: rows/wave doubled -> each staged B byte is ds_read
// by 2 waves instead of 4 -> LDS-read pipe halves (was the largest pipe,
// ~20us/CU). exp2 kept on the trans pipe (r21: polynomial regressed).
// 8 stages of 16 KB double-buffered (32 KB LDS, 5 blocks/CU).
// mfma_scale_16x16x128 FP4 (cbsz=4, blgp=4), E8M0 scales 0x7B = 2^-4.
// Frag: lane l holds row (l&15), K-chunk (l>>4), data in dwords 0..3.
// C/D: col = lane&15, row = (lane>>4)*4 + reg.
__global__ __launch_bounds__(256, 4) void gemm_expsum(
    const uchar* __restrict__ A4,   // ohat fp4 tiled (x16*log2e)
    const uchar* __restrict__ B4,   // that fp4 tiled (x16)
    float* __restrict__ partial) {
  __shared__ __align__(16) uchar Bs[2][16384];  // 2 x 16 KB

  int b   = blockIdx.x;
  int xcd = b & 7;
  int idx = b >> 3;               // 0..255
  int bm  = xcd * 16 + (idx & 15);
  int bnr = idx >> 4;             // 0..15

  int tid  = threadIdx.x;
  int lane = tid & 63;
  int wid  = tid >> 6;            // 0..3
  int wr   = wid & 1;             // 64-row strip (4 row-groups)
  int wch  = wid >> 1;            // 64-col half of each 128-col stage

  const uchar* Ap = A4 + (size_t)(bm * 8 + wr * 4) * 2048 + (size_t)lane * 16;
  const uchar* Bg = B4 + (size_t)bnr * 131072;   // 128 KB strip (1024 cols)

  // persistent A fragments: af[group][kt], data 4 dwords (upper dead for FP4)
  i32x8 af[4][2];
#pragma unroll
  for (int g = 0; g < 4; ++g)
#pragma unroll
    for (int kt = 0; kt < 2; ++kt) {
      int4 d = *reinterpret_cast<const int4*>(Ap + g * 2048 + kt * 1024);
      af[g][kt] = (i32x8){d.x, d.y, d.z, d.w, 0, 0, 0, 0};
    }

  f32x2 v2[8];
#pragma unroll
  for (int j = 0; j < 8; ++j) v2[j] = (f32x2){0.f, 0.f};

  const f32x4 zero4 = {0.f, 0.f, 0.f, 0.f};
  i32x8 b0 = (i32x8){0, 0, 0, 0, 0, 0, 0, 0};
  i32x8 b1 = (i32x8){0, 0, 0, 0, 0, 0, 0, 0};

  // stage st (16 KB = 128 cols): 4 passes x (256 thr x 16B), linear both sides.
#define STAGE(st, s)                                                           \
  {                                                                            \
    _Pragma("unroll") for (int p = 0; p < 4; ++p)                              \
        gload_lds16(Bg + (size_t)(st) * 16384 + p * 4096 + wid * 1024 +        \
                        lane * 16,                                             \
                    (char*)Bs[s] + p * 4096 + wid * 1024 + lane * 16);         \
  }

#define COMPUTE(s)                                                             \
  {                                                                            \
    const uchar* bb = Bs[s];                                                   \
    _Pragma("unroll") for (int nn = 0; nn < 4; ++nn) {                         \
      const uchar* cb = bb + (wch * 4 + nn) * 2048 + lane * 16;                \
      *reinterpret_cast<int4*>(&b0) = *reinterpret_cast<const int4*>(cb);      \
      *reinterpret_cast<int4*>(&b1) = *reinterpret_cast<const int4*>(cb + 1024); \
      _Pragma("unroll") for (int g = 0; g < 4; ++g) {                          \
        f32x4 ag = __builtin_amdgcn_mfma_scale_f32_16x16x128_f8f6f4(           \
            af[g][0], b0, zero4, 4, 4, 0, 0x7B7B7B7B, 0, 0x7B7B7B7B);          \
        ag = __builtin_amdgcn_mfma_scale_f32_16x16x128_f8f6f4(                 \
            af[g][1], b1, ag, 4, 4, 0, 0x7B7B7B7B, 0, 0x7B7B7B7B);             \
        v2[2 * g]     += (f32x2){EXP2(ag[0]), EXP2(ag[1])};                    \
        v2[2 * g + 1] += (f32x2){EXP2(ag[2]), EXP2(ag[3])};                    \
      }                                                                        \
    }                                                                          \
  }

  STAGE(0, 0);
  __syncthreads();                 // stage 0 resident
#pragma unroll
  for (int st = 0; st < NSTG; ++st) {
    if (st < NSTG - 1) STAGE(st + 1, (st + 1) & 1);  // async into other buffer
    COMPUTE(st & 1);
    if (st < NSTG - 1) __syncthreads();  // drain stage(st+1); readers of st done
  }
#undef STAGE
#undef COMPUTE

  // ---- bisect butterfly over the 16 fragment columns (r5/r6-verified) ----
  // 15 shfl; lane ends with the full column-sum of entry j = lane&15.
  float v[16];
#pragma unroll
  for (int j = 0; j < 16; ++j) v[j] = v2[j >> 1][j & 1];
#pragma unroll
  for (int s = 0; s < 4; ++s) {
    const int len = 16 >> s;
    const int bit = (lane >> s) & 1;
#pragma unroll
    for (int t = 0; t < 8; ++t) {
      if (t < (len >> 1)) {
        float a = v[2 * t], b2 = v[2 * t + 1];
        float recv = __shfl_xor(bit ? a : b2, 1 << s);
        v[t] = (bit ? b2 : a) + recv;
      }
    }
  }
  {
    int j   = lane & 15;           // g = j>>2, reg = j&3
    int sub = lane >> 4;           // 0..3
    int row = bm * BM + wr * 64 + (j >> 2) * 16 + sub * 4 + (j & 3);
    partial[(size_t)row * NCHUNK + ((bnr << 1) | wch)] = v[0];
  }
}

// ---------------- Kernel C: per-row finish: log(sum) - exact diag ----------
__global__ void row_finish(const float* __restrict__ partial,
                           const float* __restrict__ dlog,
                           float* __restrict__ rowloss) {
  int row = blockIdx.x * 256 + threadIdx.x;
  const float4* p = reinterpret_cast<const float4*>(partial + (size_t)row * NCHUNK);
  float s = 0.f;
#pragma unroll
  for (int q = 0; q < 8; ++q) {
    float4 pq = p[q];
    s += (pq.x + pq.y) + (pq.z + pq.w);
  }
  rowloss[row] = logf(s) - dlog[row];
}

// ---------------- Kernel D: mean over rows -> d_out[0] ----------------
__global__ void final_reduce(const float* __restrict__ rl, float* __restrict__ out) {
  __shared__ float sm[16];
  float s = 0.f;
  for (int i = threadIdx.x; i < BROWS; i += 1024) s += rl[i];
#pragma unroll
  for (int m = 1; m < 64; m <<= 1) s += __shfl_xor(s, m);
  int wid = threadIdx.x >> 6, lane = threadIdx.x & 63;
  if (lane == 0) sm[wid] = s;
  __syncthreads();
  if (wid == 0) {
    float v = (lane < 16) ? sm[lane] : 0.f;
#pragma unroll
    for (int m = 1; m < 16; m <<= 1) v += __shfl_xor(v, m);
    if (lane == 0) out[0] = v / (float)BROWS;
  }
}

extern "C" void kernel_launch(void* const* d_in, const int* in_sizes, int n_in,
                              void* d_out, int out_size, void* d_ws, size_t ws_size,
                              hipStream_t stream) {
  const float* outputs = (const float*)d_in[0];
  const float* targets = (const float*)d_in[1];
  float* out = (float*)d_out;
  char* ws = (char*)d_ws;

  uchar* o4      = (uchar*)ws;                                      // 2 MB (tiled fp4)
  uchar* t4      = (uchar*)(ws + (size_t)2 * 1024 * 1024);          // 2 MB (tiled fp4)
  float* partial = (float*)(ws + (size_t)4 * 1024 * 1024);          // 2 MB
  float* dlog    = (float*)(ws + (size_t)6 * 1024 * 1024);          // 64 KB
  float* rowloss = (float*)(ws + (size_t)6 * 1024 * 1024 + 65536);  // 64 KB

  normalize_both<<<BROWS / 4, 256, 0, stream>>>(outputs, targets, o4, t4, dlog);
  gemm_expsum<<<NBM * NBNR, 256, 0, stream>>>(o4, t4, partial);
  row_finish<<<BROWS / 256, 256, 0, stream>>>(partial, dlog, rowloss);
  final_reduce<<<1, 1024, 0, stream>>>(rowloss, out);
}